// Round 4
// baseline (188.223 us; speedup 1.0000x reference)
//
#include <hip/hip_runtime.h>

#define BB 4096
#define TT 10
#define SS 301
#define HH 5
#define OO 3
#define NHALF (2048 * SS)   // 616448 == (B*S)/2 ; sample2 = sample1 + NHALF (b2 = b+2048, same s)

typedef float f2 __attribute__((ext_vector_type(2)));

__device__ __forceinline__ f2 mk2(float a, float b){ f2 r; r.x = a; r.y = b; return r; }
__device__ __forceinline__ f2 sp2(float a){ f2 r; r.x = a; r.y = a; return r; }
__device__ __forceinline__ f2 fma2(f2 a, f2 b, f2 c){ return __builtin_elementwise_fma(a, b, c); }

// 1/d elementwise, d > 0 (here d in [1.3e5, 3.6e6]): magic seed + 3 Newton steps.
// 3 iterations: converges below fp32 eps even from a ~50%-error seed.
__device__ __forceinline__ f2 rcp2(f2 d){
    f2 y = mk2(__uint_as_float(0x7EF311C3u - __float_as_uint(d.x)),
               __uint_as_float(0x7EF311C3u - __float_as_uint(d.y)));
    y = y * fma2(-d, y, sp2(2.0f));
    y = y * fma2(-d, y, sp2(2.0f));
    y = y * fma2(-d, y, sp2(2.0f));
    return y;
}

// tanh via Pade[7/6] (Lambert continued fraction, depth 7), arg clamped to [-4.8, 4.8].
// Abs err <= ~1.4e-4 including the clamp tail (1 - tanh(4.8) = 1.35e-4).
__device__ __forceinline__ f2 tanh2(f2 x){
    f2 t = __builtin_elementwise_min(__builtin_elementwise_max(x, sp2(-4.8f)), sp2(4.8f));
    f2 s = t * t;
    f2 nu = fma2(fma2(s + sp2(378.0f), s, sp2(17325.0f)), s, sp2(135135.0f)) * t;
    f2 de = fma2(fma2(fma2(sp2(28.0f), s, sp2(3150.0f)), s, sp2(62370.0f)), s, sp2(135135.0f));
    return nu * rcp2(de);
}

// sigma(a) = 0.5 + 0.5 * tanh(a/2)
__device__ __forceinline__ f2 sigmoid2(f2 a){
    return fma2(tanh2(a * sp2(0.5f)), sp2(0.5f), sp2(0.5f));
}

__global__ __launch_bounds__(256) void gru_kernel(
    const float* __restrict__ x,
    const float* __restrict__ w_ih,
    const float* __restrict__ w_hh,
    const float* __restrict__ b_ih,
    const float* __restrict__ b_hh,
    const float* __restrict__ fc_w,
    const float* __restrict__ fc_b,
    float* __restrict__ out)
{
    const int n = blockIdx.x * blockDim.x + threadIdx.x;   // 0 .. NHALF-1
    if (n >= NHALF) return;
    const int b = n / SS;          // 0 .. 2047
    const int s = n - b * SS;

    // Wave-uniform weights: plain scalars -> SGPRs, broadcast into packed ops.
    float wr[HH], wz[HH], wn[HH];
    float br_[HH], bz_[HH], bi_[HH], bh_[HH];
    float whr[HH][HH], whz[HH][HH], whn[HH][HH];

    #pragma unroll
    for (int j = 0; j < HH; ++j) {
        wr[j] = w_ih[j];
        wz[j] = w_ih[HH + j];
        wn[j] = w_ih[2 * HH + j];
        br_[j] = b_ih[j]        + b_hh[j];
        bz_[j] = b_ih[HH + j]   + b_hh[HH + j];
        bi_[j] = b_ih[2 * HH + j];
        bh_[j] = b_hh[2 * HH + j];
        #pragma unroll
        for (int k = 0; k < HH; ++k) {
            whr[j][k] = w_hh[j * HH + k];
            whz[j][k] = w_hh[(HH + j) * HH + k];
            whn[j][k] = w_hh[(2 * HH + j) * HH + k];
        }
    }

    // Preload x for both samples; each stream is coalesced across the wave.
    const float* xp = x + (size_t)b * (TT * SS) + s;
    const size_t x2off = (size_t)2048 * TT * SS;   // sample2: b+2048
    f2 xt[TT];
    #pragma unroll
    for (int t = 0; t < TT; ++t) xt[t] = mk2(xp[t * SS], xp[t * SS + x2off]);

    f2 h[HH];
    #pragma unroll
    for (int j = 0; j < HH; ++j) h[j] = sp2(0.0f);

    #pragma unroll
    for (int t = 0; t < TT; ++t) {
        const f2 xd = xt[t];
        f2 hn[HH];
        #pragma unroll
        for (int j = 0; j < HH; ++j) {
            f2 ar = fma2(xd, sp2(wr[j]), sp2(br_[j]));
            f2 az = fma2(xd, sp2(wz[j]), sp2(bz_[j]));
            f2 an = fma2(xd, sp2(wn[j]), sp2(bi_[j]));
            f2 ah = sp2(bh_[j]);
            #pragma unroll
            for (int k = 0; k < HH; ++k) {
                ar = fma2(h[k], sp2(whr[j][k]), ar);
                az = fma2(h[k], sp2(whz[j][k]), az);
                ah = fma2(h[k], sp2(whn[j][k]), ah);
            }
            f2 r  = sigmoid2(ar);
            f2 z  = sigmoid2(az);
            f2 nv = tanh2(fma2(r, ah, an));
            hn[j] = fma2(z, h[j] - nv, nv);   // (1-z)n + z h
        }
        #pragma unroll
        for (int j = 0; j < HH; ++j) h[j] = hn[j];
    }

    // y = fc(h); out[(b*O + o)*S + s], second sample at b+2048.
    float* op = out + (size_t)b * (OO * SS) + s;
    const size_t o2off = (size_t)2048 * OO * SS;
    #pragma unroll
    for (int o = 0; o < OO; ++o) {
        f2 y = sp2(fc_b[o]);
        #pragma unroll
        for (int k = 0; k < HH; ++k) y = fma2(sp2(fc_w[o * HH + k]), h[k], y);
        op[o * SS]         = y.x;
        op[o * SS + o2off] = y.y;
    }
}

extern "C" void kernel_launch(void* const* d_in, const int* in_sizes, int n_in,
                              void* d_out, int out_size, void* d_ws, size_t ws_size,
                              hipStream_t stream) {
    const float* x    = (const float*)d_in[0];
    const float* w_ih = (const float*)d_in[1];
    const float* w_hh = (const float*)d_in[2];
    const float* b_ih = (const float*)d_in[3];
    const float* b_hh = (const float*)d_in[4];
    const float* fc_w = (const float*)d_in[5];
    const float* fc_b = (const float*)d_in[6];
    float* out = (float*)d_out;

    const int block = 256;
    const int grid = NHALF / block;   // 2408 exactly
    gru_kernel<<<grid, block, 0, stream>>>(x, w_ih, w_hh, b_ih, b_hh, fc_w, fc_b, out);
}